// Round 4
// baseline (321.737 us; speedup 1.0000x reference)
//
#include <hip/hip_runtime.h>

// Problem constants (GATConv_17635135717523)
// N=50000 nodes, E=800000 edges, IN=256, H=8, O=32, H*O=256
#define N_NODES 50000
#define N_EDGES 800000
#define NPAD    50176   // 1024*49

typedef __bf16 bf16x8 __attribute__((ext_vector_type(8)));
typedef float  fx4    __attribute__((ext_vector_type(4)));
typedef unsigned short us4 __attribute__((ext_vector_type(4)));
typedef unsigned short us8 __attribute__((ext_vector_type(8)));

__device__ __forceinline__ float b2f(unsigned short u) {
    return __uint_as_float(((unsigned)u) << 16);
}
__device__ __forceinline__ unsigned short f2b(float f) {
    unsigned x = __float_as_uint(f);
    return (unsigned short)((x + 0x7FFFu + ((x >> 16) & 1u)) >> 16);
}

// ------------------------------------------------------- W prep (merged)
// blocks 0..255: Wt[n][k] = bf16(W[k][n])  (n-major, k contiguous)
// blocks 256..271: M2t[j][k] hi/lo, j<8 -> el head j, j>=8 -> er head j-8
__global__ __launch_bounds__(256) void prep_w(
    const float* __restrict__ W,
    const float* __restrict__ attn_l, const float* __restrict__ attn_r,
    unsigned short* __restrict__ Wt,
    unsigned short* __restrict__ M2t_hi, unsigned short* __restrict__ M2t_lo) {
    int b = blockIdx.x, k = threadIdx.x;
    if (b < 256) {
        Wt[b * 256 + k] = f2b(W[k * 256 + b]);
    } else {
        int j = b - 256;
        const float* av = (j < 8) ? (attn_l + j * 32) : (attn_r + (j - 8) * 32);
        int c0 = (j & 7) * 32;
        float s = 0.f;
#pragma unroll
        for (int o = 0; o < 32; ++o) s += W[k * 256 + c0 + o] * av[o];
        unsigned short h = f2b(s);
        M2t_hi[j * 256 + k] = h;
        M2t_lo[j * 256 + k] = f2b(s - b2f(h));
    }
}

// ------------------------------------------------------- fused GEMM
// ft = bf16(feat @ W); el/er = feat @ M2 (fp32 out, M2 in hi+lo bf16).
// Block: 64 rows x 256 cols, 4 waves (wave w owns cols [w*64,w*64+64)).
// feat fp32 -> bf16 LDS tile [64][40], double-buffered, 1 barrier/K-iter.
__global__ __launch_bounds__(256) void gemm_ft(
    const float* __restrict__ feat,
    const unsigned short* __restrict__ Wt,
    const unsigned short* __restrict__ M2t_hi,
    const unsigned short* __restrict__ M2t_lo,
    unsigned short* __restrict__ ft,
    float* __restrict__ el, float* __restrict__ er) {
    __shared__ unsigned short Alds[2][64 * 40];
    const int tid  = threadIdx.x;
    const int lane = tid & 63;
    const int wid  = tid >> 6;
    const int quad = lane >> 4, l15 = lane & 15;
    const int mbase = blockIdx.x * 64;
    const int nbase = wid * 64;

    fx4 acc[4][4];
    fx4 acce[4];
#pragma unroll
    for (int i = 0; i < 4; ++i) {
        acce[i] = (fx4)0.0f;
#pragma unroll
        for (int j = 0; j < 4; ++j) acc[i][j] = (fx4)0.0f;
    }

    // staging role: thread -> (row, 8-elem k segment)
    const int srow  = tid >> 2;
    const int skseg = (tid & 3) * 8;
    int grow = mbase + srow;
    grow = grow < N_NODES ? grow : N_NODES - 1;
    const float* sp = feat + (size_t)grow * 256 + skseg;
    const int sdoff = srow * 40 + skseg;

    // prologue: stage k0 = 0 into buf 0
    {
        float4 f0 = *reinterpret_cast<const float4*>(sp);
        float4 f1 = *reinterpret_cast<const float4*>(sp + 4);
        us8 pk;
        pk[0] = f2b(f0.x); pk[1] = f2b(f0.y); pk[2] = f2b(f0.z); pk[3] = f2b(f0.w);
        pk[4] = f2b(f1.x); pk[5] = f2b(f1.y); pk[6] = f2b(f1.z); pk[7] = f2b(f1.w);
        *reinterpret_cast<us8*>(&Alds[0][sdoff]) = pk;
    }

    int p = 0;
    for (int k0 = 0; k0 < 256; k0 += 32) {
        float4 g0, g1;
        const bool more = (k0 + 32) < 256;
        if (more) {
            g0 = *reinterpret_cast<const float4*>(sp + k0 + 32);
            g1 = *reinterpret_cast<const float4*>(sp + k0 + 36);
        }
        __syncthreads();   // buf[p] writes visible; prior reads of buf[p^1] done

        const int krow = k0 + quad * 8;
        bf16x8 a[4], b[4];
#pragma unroll
        for (int mt = 0; mt < 4; ++mt)
            a[mt] = *reinterpret_cast<const bf16x8*>(&Alds[p][(mt * 16 + l15) * 40 + quad * 8]);
#pragma unroll
        for (int nt = 0; nt < 4; ++nt)
            b[nt] = *reinterpret_cast<const bf16x8*>(Wt + (nbase + nt * 16 + l15) * 256 + krow);
#pragma unroll
        for (int mt = 0; mt < 4; ++mt)
#pragma unroll
            for (int nt = 0; nt < 4; ++nt)
                acc[mt][nt] = __builtin_amdgcn_mfma_f32_16x16x32_bf16(
                    a[mt], b[nt], acc[mt][nt], 0, 0, 0);
        if (wid == 0) {
            bf16x8 bh = *reinterpret_cast<const bf16x8*>(M2t_hi + l15 * 256 + krow);
            bf16x8 bl = *reinterpret_cast<const bf16x8*>(M2t_lo + l15 * 256 + krow);
#pragma unroll
            for (int mt = 0; mt < 4; ++mt) {
                acce[mt] = __builtin_amdgcn_mfma_f32_16x16x32_bf16(a[mt], bh, acce[mt], 0, 0, 0);
                acce[mt] = __builtin_amdgcn_mfma_f32_16x16x32_bf16(a[mt], bl, acce[mt], 0, 0, 0);
            }
        }
        if (more) {
            us8 pk;
            pk[0] = f2b(g0.x); pk[1] = f2b(g0.y); pk[2] = f2b(g0.z); pk[3] = f2b(g0.w);
            pk[4] = f2b(g1.x); pk[5] = f2b(g1.y); pk[6] = f2b(g1.z); pk[7] = f2b(g1.w);
            *reinterpret_cast<us8*>(&Alds[p ^ 1][sdoff]) = pk;
        }
        p ^= 1;
    }

    // C/D layout: col = lane&15, row = (lane>>4)*4 + reg  [verified m89/m91]
#pragma unroll
    for (int mt = 0; mt < 4; ++mt) {
#pragma unroll
        for (int r = 0; r < 4; ++r) {
            int row = mbase + mt * 16 + quad * 4 + r;
            if (row < N_NODES) {
#pragma unroll
                for (int nt = 0; nt < 4; ++nt)
                    ft[(size_t)row * 256 + nbase + nt * 16 + l15] = f2b(acc[mt][nt][r]);
            }
        }
    }
    if (wid == 0) {
#pragma unroll
        for (int mt = 0; mt < 4; ++mt) {
#pragma unroll
            for (int r = 0; r < 4; ++r) {
                int row = mbase + mt * 16 + quad * 4 + r;
                if (row < N_NODES) {
                    float v = acce[mt][r];
                    if (l15 < 8) el[row * 8 + l15] = v;
                    else         er[row * 8 + (l15 - 8)] = v;
                }
            }
        }
    }
}

// ------------------------------------------------------- CSR build
__global__ __launch_bounds__(256) void count_deg(
    const int* __restrict__ dst, int* __restrict__ cnt) {
    int t = blockIdx.x * 256 + threadIdx.x;
    if (t < N_EDGES) atomicAdd(&cnt[dst[t]], 1);
}

// Single-block exclusive scan over NPAD counts: 1024 threads x 49 elems.
__global__ __launch_bounds__(1024) void scan_all(
    const int* __restrict__ cnt, int* __restrict__ off, int* __restrict__ cursor) {
    __shared__ int ps[1024];
    int t = threadIdx.x;
    int base = t * 49;
    int loc[49];
    int s = 0;
#pragma unroll
    for (int i = 0; i < 49; ++i) { loc[i] = cnt[base + i]; s += loc[i]; }
    ps[t] = s;
    __syncthreads();
    for (int d = 1; d < 1024; d <<= 1) {
        int add = (t >= d) ? ps[t - d] : 0;
        __syncthreads();
        ps[t] += add;
        __syncthreads();
    }
    int run = ps[t] - s;   // exclusive prefix of this thread's chunk
#pragma unroll
    for (int i = 0; i < 49; ++i) {
        off[base + i] = run;
        cursor[base + i] = run;
        run += loc[i];
    }
}

__global__ __launch_bounds__(256) void bucket_edges(
    const int* __restrict__ src, const int* __restrict__ dst,
    int* __restrict__ cursor, int* __restrict__ inedge_src) {
    int t = blockIdx.x * 256 + threadIdx.x;
    if (t < N_EDGES) {
        int d = dst[t];
        int p = atomicAdd(&cursor[d], 1);
        inedge_src[p] = src[t];
    }
}

// ------------------------------------------------------- aggregation v3
// One wave per dst node, SINGLE edge pass: softmax denom accumulated inline
// (division deferred to epilogue; no max-subtraction needed, |logit| ~ O(1)).
// lane owns out elems [lane*4, lane*4+4), head h = lane>>3.
// Unroll x8: 8 coalesced 512B ft-row gathers in flight per wave. No LDS.
__global__ __launch_bounds__(256) void aggregate(
    const unsigned short* __restrict__ ft,
    const float* __restrict__ el, const float* __restrict__ er,
    const int* __restrict__ off, const int* __restrict__ cnt,
    const int* __restrict__ inedge_src,
    const float* __restrict__ bias,
    float* __restrict__ out) {
    int wid = threadIdx.x >> 6, lane = threadIdx.x & 63;
    int v = blockIdx.x * 4 + wid;          // grid exact: v < N always
    int start = off[v], deg = cnt[v];
    int h = lane >> 3;
    float erv = er[v * 8 + h];
    const int* ip = inedge_src + start;
    const us4* ftv = reinterpret_cast<const us4*>(ft);

    float a0 = 0.f, a1 = 0.f, a2 = 0.f, a3 = 0.f, s = 0.f;
    int j = 0;
    for (; j + 8 <= deg; j += 8) {
        int u[8];
#pragma unroll
        for (int t = 0; t < 8; ++t) u[t] = ip[j + t];
        us4 f[8];
#pragma unroll
        for (int t = 0; t < 8; ++t) f[t] = ftv[(size_t)u[t] * 64 + lane];
        float w[8];
#pragma unroll
        for (int t = 0; t < 8; ++t) {
            float x = el[u[t] * 8 + h] + erv;
            x = x > 0.f ? x : 0.2f * x;
            w[t] = __expf(x);
            s += w[t];
        }
#pragma unroll
        for (int t = 0; t < 8; ++t) {
            a0 += w[t] * b2f(f[t].x);
            a1 += w[t] * b2f(f[t].y);
            a2 += w[t] * b2f(f[t].z);
            a3 += w[t] * b2f(f[t].w);
        }
    }
    for (; j + 4 <= deg; j += 4) {
        int u[4];
#pragma unroll
        for (int t = 0; t < 4; ++t) u[t] = ip[j + t];
        us4 f[4];
#pragma unroll
        for (int t = 0; t < 4; ++t) f[t] = ftv[(size_t)u[t] * 64 + lane];
#pragma unroll
        for (int t = 0; t < 4; ++t) {
            float x = el[u[t] * 8 + h] + erv;
            x = x > 0.f ? x : 0.2f * x;
            float w = __expf(x);
            s += w;
            a0 += w * b2f(f[t].x);
            a1 += w * b2f(f[t].y);
            a2 += w * b2f(f[t].z);
            a3 += w * b2f(f[t].w);
        }
    }
    for (; j < deg; ++j) {
        int u = ip[j];
        us4 f = ftv[(size_t)u * 64 + lane];
        float x = el[u * 8 + h] + erv;
        x = x > 0.f ? x : 0.2f * x;
        float w = __expf(x);
        s += w;
        a0 += w * b2f(f.x);
        a1 += w * b2f(f.y);
        a2 += w * b2f(f.z);
        a3 += w * b2f(f.w);
    }
    float inv = deg > 0 ? 1.0f / s : 0.f;
    float4 bb = reinterpret_cast<const float4*>(bias)[lane];
    float4 o;
    o.x = a0 * inv + bb.x; o.y = a1 * inv + bb.y;
    o.z = a2 * inv + bb.z; o.w = a3 * inv + bb.w;
    reinterpret_cast<float4*>(out)[(size_t)v * 64 + lane] = o;
}

// ------------------------------------------------------- launch
extern "C" void kernel_launch(void* const* d_in, const int* in_sizes, int n_in,
                              void* d_out, int out_size, void* d_ws, size_t ws_size,
                              hipStream_t stream) {
    const float* feat   = (const float*)d_in[0];
    const float* W      = (const float*)d_in[1];
    const float* attn_l = (const float*)d_in[2];
    const float* attn_r = (const float*)d_in[3];
    const float* bias   = (const float*)d_in[4];
    const int* src = (const int*)d_in[5];
    const int* dst = (const int*)d_in[6];
    float* out = (float*)d_out;

    char* ws = (char*)d_ws;
    // workspace layout (16B aligned), ~32.8 MB total
    unsigned short* Wt     = (unsigned short*)(ws + 0);          //    131,072
    unsigned short* M2t_hi = (unsigned short*)(ws + 131072);     //      8,192
    unsigned short* M2t_lo = (unsigned short*)(ws + 139264);     //      8,192
    unsigned short* ft     = (unsigned short*)(ws + 147456);     // 25,600,000
    float* el              = (float*)(ws + 25747456);            //  1,600,000
    float* er              = (float*)(ws + 27347456);            //  1,600,000
    int* cnt               = (int*)(ws + 28947456);              //    200,704
    int* off               = (int*)(ws + 29148160);              //    200,704
    int* cursor            = (int*)(ws + 29348864);              //    200,704
    int* inedge_src        = (int*)(ws + 29549568);              //  3,200,000

    hipMemsetAsync(cnt, 0, NPAD * sizeof(int), stream);

    prep_w<<<272, 256, 0, stream>>>(W, attn_l, attn_r, Wt, M2t_hi, M2t_lo);
    gemm_ft<<<782, 256, 0, stream>>>(feat, Wt, M2t_hi, M2t_lo, ft, el, er);
    count_deg<<<3125, 256, 0, stream>>>(dst, cnt);
    scan_all<<<1, 1024, 0, stream>>>(cnt, off, cursor);
    bucket_edges<<<3125, 256, 0, stream>>>(src, dst, cursor, inedge_src);
    aggregate<<<12500, 256, 0, stream>>>(ft, el, er, off, cnt, inedge_src, bias, out);
}

// Round 5
// 294.364 us; speedup vs baseline: 1.0930x; 1.0930x over previous
//
#include <hip/hip_runtime.h>

// Problem constants (GATConv_17635135717523)
// N=50000 nodes, E=800000 edges, IN=256, H=8, O=32, H*O=256
#define N_NODES 50000
#define N_EDGES 800000
#define NPAD    50176   // 196*256

typedef __bf16 bf16x8 __attribute__((ext_vector_type(8)));
typedef float  fx4    __attribute__((ext_vector_type(4)));
typedef unsigned short us4 __attribute__((ext_vector_type(4)));
typedef unsigned short us8 __attribute__((ext_vector_type(8)));

__device__ __forceinline__ float b2f(unsigned short u) {
    return __uint_as_float(((unsigned)u) << 16);
}
__device__ __forceinline__ unsigned short f2b(float f) {
    unsigned x = __float_as_uint(f);
    return (unsigned short)((x + 0x7FFFu + ((x >> 16) & 1u)) >> 16);
}

// ------------------------------------------------------- W prep (merged)
// blocks 0..255: Wt[n][k] = bf16(W[k][n])  (n-major, k contiguous)
// blocks 256..271: M2t[j][k] hi/lo, j<8 -> el head j, j>=8 -> er head j-8
__global__ __launch_bounds__(256) void prep_w(
    const float* __restrict__ W,
    const float* __restrict__ attn_l, const float* __restrict__ attn_r,
    unsigned short* __restrict__ Wt,
    unsigned short* __restrict__ M2t_hi, unsigned short* __restrict__ M2t_lo) {
    int b = blockIdx.x, k = threadIdx.x;
    if (b < 256) {
        Wt[b * 256 + k] = f2b(W[k * 256 + b]);
    } else {
        int j = b - 256;
        const float* av = (j < 8) ? (attn_l + j * 32) : (attn_r + (j - 8) * 32);
        int c0 = (j & 7) * 32;
        float s = 0.f;
#pragma unroll
        for (int o = 0; o < 32; ++o) s += W[k * 256 + c0 + o] * av[o];
        unsigned short h = f2b(s);
        M2t_hi[j * 256 + k] = h;
        M2t_lo[j * 256 + k] = f2b(s - b2f(h));
    }
}

// ------------------------------------------------------- fused GEMM (r3 form)
// ft = bf16(feat @ W); el/er = feat @ M2 (fp32 out, M2 in hi+lo bf16).
// Block: 64 rows x 256 cols, 4 waves (wave w owns cols [w*64,w*64+64)).
// feat fp32 staged -> bf16 LDS tile [64][40] (pad 32->40).
__global__ __launch_bounds__(256) void gemm_ft(
    const float* __restrict__ feat,
    const unsigned short* __restrict__ Wt,
    const unsigned short* __restrict__ M2t_hi,
    const unsigned short* __restrict__ M2t_lo,
    unsigned short* __restrict__ ft,
    float* __restrict__ el, float* __restrict__ er) {
    __shared__ unsigned short Alds[64 * 40];
    const int tid  = threadIdx.x;
    const int lane = tid & 63;
    const int wid  = tid >> 6;
    const int quad = lane >> 4, l15 = lane & 15;
    const int mbase = blockIdx.x * 64;
    const int nbase = wid * 64;

    fx4 acc[4][4];
    fx4 acce[4];
#pragma unroll
    for (int i = 0; i < 4; ++i) {
        acce[i] = (fx4)0.0f;
#pragma unroll
        for (int j = 0; j < 4; ++j) acc[i][j] = (fx4)0.0f;
    }

    // staging role: thread -> (row, 8-elem k segment)
    const int srow  = tid >> 2;
    const int skseg = (tid & 3) * 8;
    int grow = mbase + srow;
    grow = grow < N_NODES ? grow : N_NODES - 1;
    const float* sp = feat + (size_t)grow * 256 + skseg;
    unsigned short* sdst = &Alds[srow * 40 + skseg];

    for (int k0 = 0; k0 < 256; k0 += 32) {
        __syncthreads();
        float4 f0 = *reinterpret_cast<const float4*>(sp + k0);
        float4 f1 = *reinterpret_cast<const float4*>(sp + k0 + 4);
        us8 pk;
        pk[0] = f2b(f0.x); pk[1] = f2b(f0.y); pk[2] = f2b(f0.z); pk[3] = f2b(f0.w);
        pk[4] = f2b(f1.x); pk[5] = f2b(f1.y); pk[6] = f2b(f1.z); pk[7] = f2b(f1.w);
        *reinterpret_cast<us8*>(sdst) = pk;
        __syncthreads();

        const int krow = k0 + quad * 8;
        bf16x8 a[4], b[4];
#pragma unroll
        for (int mt = 0; mt < 4; ++mt)
            a[mt] = *reinterpret_cast<const bf16x8*>(&Alds[(mt * 16 + l15) * 40 + quad * 8]);
#pragma unroll
        for (int nt = 0; nt < 4; ++nt)
            b[nt] = *reinterpret_cast<const bf16x8*>(Wt + (nbase + nt * 16 + l15) * 256 + krow);
#pragma unroll
        for (int mt = 0; mt < 4; ++mt)
#pragma unroll
            for (int nt = 0; nt < 4; ++nt)
                acc[mt][nt] = __builtin_amdgcn_mfma_f32_16x16x32_bf16(
                    a[mt], b[nt], acc[mt][nt], 0, 0, 0);
        if (wid == 0) {
            bf16x8 bh = *reinterpret_cast<const bf16x8*>(M2t_hi + l15 * 256 + krow);
            bf16x8 bl = *reinterpret_cast<const bf16x8*>(M2t_lo + l15 * 256 + krow);
#pragma unroll
            for (int mt = 0; mt < 4; ++mt) {
                acce[mt] = __builtin_amdgcn_mfma_f32_16x16x32_bf16(a[mt], bh, acce[mt], 0, 0, 0);
                acce[mt] = __builtin_amdgcn_mfma_f32_16x16x32_bf16(a[mt], bl, acce[mt], 0, 0, 0);
            }
        }
    }

    // C/D layout: col = lane&15, row = (lane>>4)*4 + reg  [verified m89/m91]
#pragma unroll
    for (int mt = 0; mt < 4; ++mt) {
#pragma unroll
        for (int r = 0; r < 4; ++r) {
            int row = mbase + mt * 16 + quad * 4 + r;
            if (row < N_NODES) {
#pragma unroll
                for (int nt = 0; nt < 4; ++nt)
                    ft[(size_t)row * 256 + nbase + nt * 16 + l15] = f2b(acc[mt][nt][r]);
            }
        }
    }
    if (wid == 0) {
#pragma unroll
        for (int mt = 0; mt < 4; ++mt) {
#pragma unroll
            for (int r = 0; r < 4; ++r) {
                int row = mbase + mt * 16 + quad * 4 + r;
                if (row < N_NODES) {
                    float v = acce[mt][r];
                    if (l15 < 8) el[row * 8 + l15] = v;
                    else         er[row * 8 + (l15 - 8)] = v;
                }
            }
        }
    }
}

// ------------------------------------------------------- CSR build
__global__ __launch_bounds__(256) void count_deg(
    const int* __restrict__ dst, int* __restrict__ cnt) {
    int t = blockIdx.x * 256 + threadIdx.x;
    if (t < N_EDGES / 4) {
        int4 d = reinterpret_cast<const int4*>(dst)[t];
        atomicAdd(&cnt[d.x], 1);
        atomicAdd(&cnt[d.y], 1);
        atomicAdd(&cnt[d.z], 1);
        atomicAdd(&cnt[d.w], 1);
    }
}

__global__ __launch_bounds__(256) void block_sum(
    const int* __restrict__ cnt, int* __restrict__ bsum) {
    int i = blockIdx.x * 256 + threadIdx.x;
    int v = cnt[i];
#pragma unroll
    for (int off = 1; off < 64; off <<= 1) v += __shfl_xor(v, off);
    __shared__ int s[4];
    if ((threadIdx.x & 63) == 0) s[threadIdx.x >> 6] = v;
    __syncthreads();
    if (threadIdx.x == 0) bsum[blockIdx.x] = s[0] + s[1] + s[2] + s[3];
}

__global__ __launch_bounds__(256) void block_scan(
    const int* __restrict__ bsum, int* __restrict__ boff) {
    __shared__ int s[256];
    int t = threadIdx.x;
    int v = (t < 196) ? bsum[t] : 0;
    s[t] = v;
    __syncthreads();
    for (int off = 1; off < 256; off <<= 1) {
        int add = (t >= off) ? s[t - off] : 0;
        __syncthreads();
        s[t] += add;
        __syncthreads();
    }
    if (t < 196) boff[t] = s[t] - v;   // exclusive
}

__global__ __launch_bounds__(256) void scan_offsets(
    const int* __restrict__ cnt, const int* __restrict__ boff,
    int* __restrict__ off, int* __restrict__ cursor) {
    int t = threadIdx.x, lane = t & 63, wid = t >> 6;
    int i = blockIdx.x * 256 + t;
    int c = cnt[i];
    int x = c;
#pragma unroll
    for (int d = 1; d < 64; d <<= 1) {
        int y = __shfl_up(x, d);
        if (lane >= d) x += y;
    }
    __shared__ int wt[4];
    if (lane == 63) wt[wid] = x;
    __syncthreads();
    int woff = 0;
    for (int w = 0; w < wid; ++w) woff += wt[w];
    int excl = boff[blockIdx.x] + woff + x - c;
    off[i] = excl;
    cursor[i] = excl;
}

__global__ __launch_bounds__(256) void bucket_edges(
    const int* __restrict__ src, const int* __restrict__ dst,
    int* __restrict__ cursor, int* __restrict__ inedge_src) {
    int t = blockIdx.x * 256 + threadIdx.x;
    if (t < N_EDGES / 4) {
        int4 s = reinterpret_cast<const int4*>(src)[t];
        int4 d = reinterpret_cast<const int4*>(dst)[t];
        inedge_src[atomicAdd(&cursor[d.x], 1)] = s.x;
        inedge_src[atomicAdd(&cursor[d.y], 1)] = s.y;
        inedge_src[atomicAdd(&cursor[d.z], 1)] = s.z;
        inedge_src[atomicAdd(&cursor[d.w], 1)] = s.w;
    }
}

// ------------------------------------------------------- aggregation v4
// One wave per dst node, single edge pass, HALF-WAVE per edge:
// 32 lanes cover a 512B ft row at 16B/lane (us8); the two halves process
// edge pairs (j, j+1) concurrently; cross-half combine via shfl_xor(32).
// Softmax denom accumulated inline (no max-subtraction; |logit| ~ O(1)).
__global__ __launch_bounds__(256) void aggregate(
    const unsigned short* __restrict__ ft,
    const float* __restrict__ el, const float* __restrict__ er,
    const int* __restrict__ off, const int* __restrict__ cnt,
    const int* __restrict__ inedge_src,
    const float* __restrict__ bias,
    float* __restrict__ out) {
    int wid = threadIdx.x >> 6, lane = threadIdx.x & 63;
    int v = blockIdx.x * 4 + wid;          // grid exact: v < N always
    int start = off[v], deg = cnt[v];
    int half = lane >> 5, l = lane & 31;
    int h = l >> 2;                         // head of elems [l*8, l*8+8)
    float erv = er[v * 8 + h];
    const int* ip = inedge_src + start;
    const us8* ft8 = reinterpret_cast<const us8*>(ft);

    float a[8] = {0.f, 0.f, 0.f, 0.f, 0.f, 0.f, 0.f, 0.f};
    float s = 0.f;
    int j = 0;
    for (; j + 8 <= deg; j += 8) {          // 4 pairs = 8 edges per iter
        int u[4];
#pragma unroll
        for (int t = 0; t < 4; ++t) u[t] = ip[j + 2 * t + half];
        us8 f[4];
#pragma unroll
        for (int t = 0; t < 4; ++t) f[t] = ft8[(size_t)u[t] * 32 + l];
#pragma unroll
        for (int t = 0; t < 4; ++t) {
            float x = el[u[t] * 8 + h] + erv;
            x = x > 0.f ? x : 0.2f * x;
            float w = __expf(x);
            s += w;
#pragma unroll
            for (int i = 0; i < 8; ++i) a[i] += w * b2f(f[t][i]);
        }
    }
    for (; j + 2 <= deg; j += 2) {          // pair tail
        int u = ip[j + half];
        us8 f = ft8[(size_t)u * 32 + l];
        float x = el[u * 8 + h] + erv;
        x = x > 0.f ? x : 0.2f * x;
        float w = __expf(x);
        s += w;
#pragma unroll
        for (int i = 0; i < 8; ++i) a[i] += w * b2f(f[i]);
    }
    if (j < deg && half == 0) {             // odd edge: half 0 only
        int u = ip[j];
        us8 f = ft8[(size_t)u * 32 + l];
        float x = el[u * 8 + h] + erv;
        x = x > 0.f ? x : 0.2f * x;
        float w = __expf(x);
        s += w;
#pragma unroll
        for (int i = 0; i < 8; ++i) a[i] += w * b2f(f[i]);
    }
    // combine halves (both halves end with full sums)
#pragma unroll
    for (int i = 0; i < 8; ++i) a[i] += __shfl_xor(a[i], 32);
    s += __shfl_xor(s, 32);
    float inv = deg > 0 ? 1.0f / s : 0.f;

    // write: lane stores 4 floats at float4-index l*2+half of the row
    int fi = l * 2 + half;
    float4 bb = reinterpret_cast<const float4*>(bias)[fi];
    int base = half * 4;
    float4 o;
    o.x = a[base + 0] * inv + bb.x;
    o.y = a[base + 1] * inv + bb.y;
    o.z = a[base + 2] * inv + bb.z;
    o.w = a[base + 3] * inv + bb.w;
    reinterpret_cast<float4*>(out)[(size_t)v * 64 + fi] = o;
}

// ------------------------------------------------------- launch
extern "C" void kernel_launch(void* const* d_in, const int* in_sizes, int n_in,
                              void* d_out, int out_size, void* d_ws, size_t ws_size,
                              hipStream_t stream) {
    const float* feat   = (const float*)d_in[0];
    const float* W      = (const float*)d_in[1];
    const float* attn_l = (const float*)d_in[2];
    const float* attn_r = (const float*)d_in[3];
    const float* bias   = (const float*)d_in[4];
    const int* src = (const int*)d_in[5];
    const int* dst = (const int*)d_in[6];
    float* out = (float*)d_out;

    char* ws = (char*)d_ws;
    // workspace layout (16B aligned), ~32.8 MB total
    unsigned short* Wt     = (unsigned short*)(ws + 0);          //    131,072
    unsigned short* M2t_hi = (unsigned short*)(ws + 131072);     //      8,192
    unsigned short* M2t_lo = (unsigned short*)(ws + 139264);     //      8,192
    unsigned short* ft     = (unsigned short*)(ws + 147456);     // 25,600,000
    float* el              = (float*)(ws + 25747456);            //  1,600,000
    float* er              = (float*)(ws + 27347456);            //  1,600,000
    int* cnt               = (int*)(ws + 28947456);              //    200,704
    int* off               = (int*)(ws + 29148160);              //    200,704
    int* cursor            = (int*)(ws + 29348864);              //    200,704
    int* bsum              = (int*)(ws + 29549568);              //      1,024
    int* boff              = (int*)(ws + 29550592);              //      1,024
    int* inedge_src        = (int*)(ws + 29551616);              //  3,200,000

    hipMemsetAsync(cnt, 0, NPAD * sizeof(int), stream);

    prep_w<<<272, 256, 0, stream>>>(W, attn_l, attn_r, Wt, M2t_hi, M2t_lo);
    gemm_ft<<<782, 256, 0, stream>>>(feat, Wt, M2t_hi, M2t_lo, ft, el, er);
    count_deg<<<782, 256, 0, stream>>>(dst, cnt);
    block_sum<<<196, 256, 0, stream>>>(cnt, bsum);
    block_scan<<<1, 256, 0, stream>>>(bsum, boff);
    scan_offsets<<<196, 256, 0, stream>>>(cnt, boff, off, cursor);
    bucket_edges<<<782, 256, 0, stream>>>(src, dst, cursor, inedge_src);
    aggregate<<<12500, 256, 0, stream>>>(ft, el, er, off, cnt, inedge_src, bias, out);
}